// Round 1
// baseline (9578.265 us; speedup 1.0000x reference)
//
#include <hip/hip_runtime.h>

typedef __attribute__((ext_vector_type(8))) short short8;
typedef __attribute__((ext_vector_type(4))) float f32x4;

#define DI __device__ __forceinline__

// ---------------- helpers ----------------
DI unsigned short f2bf(float f) {            // RNE float->bf16
  unsigned int u = __float_as_uint(f);
  u += 0x7FFFu + ((u >> 16) & 1u);
  return (unsigned short)(u >> 16);
}

DI void gload_lds16(const void* g, void* l) { // async global->LDS, 16B/lane
  __builtin_amdgcn_global_load_lds(
      (const __attribute__((address_space(1))) unsigned int*)g,
      (__attribute__((address_space(3))) unsigned int*)l, 16, 0, 0);
}

DI float sigm(float x) { return 1.f / (1.f + __expf(-x)); }
DI float tanh_(float x) { return 1.f - 2.f / (__expf(2.f * x) + 1.f); }

// swizzled h-buffer byte offset: chunked [k>>8][r][k&255], XOR bits 4..6 by r&7
// (2-way max bank aliasing on ds_read_b128 A-fragments; producer writes the
//  same layout so global_load_lds staging is a plain linear copy)
DI int hswz(int r, int k) {
  int ch = k >> 8;
  int within = ((r << 8) | (k & 255)) << 1;
  return (ch << 15) + (within ^ ((r & 7) << 4));
}

// ---------------- sizes / workspace layout ----------------
// B=64 C=800 T=512 H=1024 IN=1600 4H=4096 TB=32768
static constexpr size_t OFF_WXT  = 0;                       // bf16 [4096][1600]
static constexpr size_t OFF_WHT  = 13107200;                // bf16 [4096][1024]
static constexpr size_t OFF_BSUM = OFF_WHT + 8388608;       // f32  [4096] (bx+bh)
static constexpr size_t OFF_XS   = OFF_BSUM + 16384;        // u32  [32768][800] (bf16 x,y interleaved)
static constexpr size_t OFF_GX   = OFF_XS + 104857600;      // f16  [32768][4096] (col-permuted)
static constexpr size_t OFF_HBUF = OFF_GX + 268435456;      // bf16 3 x [64][1024] swizzled
static constexpr size_t OFF_BAR  = OFF_HBUF + 393216;       // barrier words
static constexpr size_t WS_NEED  = OFF_BAR + 256;

// ---------------- K1: pack gate weights, transposed, to bf16 ----------------
// dst[n][k] (n-major, n = gate*1024 + col) from 4 x src[k][1024]
__global__ __launch_bounds__(256) void pack_w(
    const float* __restrict__ s0, const float* __restrict__ s1,
    const float* __restrict__ s2, const float* __restrict__ s3,
    unsigned short* __restrict__ dst, int K) {
  __shared__ float tile[32][33];
  const int tx = threadIdx.x & 31, ty = threadIdx.x >> 5;
  const int kt = blockIdx.x, nt = blockIdx.y;
  const int q = (nt * 32) >> 10;
  const float* src = (q == 0) ? s0 : (q == 1) ? s1 : (q == 2) ? s2 : s3;
  const int cbase = (nt * 32) & 1023;
#pragma unroll
  for (int i = 0; i < 4; ++i) {
    int k = kt * 32 + ty + i * 8;
    tile[ty + i * 8][tx] = src[(size_t)k * 1024 + cbase + tx];
  }
  __syncthreads();
#pragma unroll
  for (int i = 0; i < 4; ++i) {
    int n = nt * 32 + ty + i * 8;
    dst[(size_t)n * K + kt * 32 + tx] = f2bf(tile[tx][ty + i * 8]);
  }
}

// ---------------- K2: combined bias bx+bh ----------------
__global__ __launch_bounds__(256) void pack_bias(
    const float* bx0, const float* bx1, const float* bx2, const float* bx3,
    const float* bh0, const float* bh1, const float* bh2, const float* bh3,
    float* __restrict__ bsum) {
  int n = blockIdx.x * 256 + threadIdx.x;
  int q = n >> 10, j = n & 1023;
  const float* bx = (q == 0) ? bx0 : (q == 1) ? bx1 : (q == 2) ? bx2 : bx3;
  const float* bh = (q == 0) ? bh0 : (q == 1) ? bh1 : (q == 2) ? bh2 : bh3;
  bsum[n] = bx[j] + bh[j];
}

// ---------------- K3: build xs bf16 [T*B][1600] (x,y_prev interleaved) ------
__global__ __launch_bounds__(256) void xs_pack(
    const float* __restrict__ x, const float* __restrict__ y,
    unsigned int* __restrict__ xs32) {
  __shared__ float xt[32][33], yt[32][33];
  const int tx = threadIdx.x & 31, ty = threadIdx.x >> 5;
  const int tt = blockIdx.x, ct = blockIdx.y, b = blockIdx.z;
#pragma unroll
  for (int i = 0; i < 4; ++i) {
    int c = ct * 32 + ty + i * 8;
    int t = tt * 32 + tx;
    size_t base = ((size_t)b * 800 + c) * 512;
    xt[ty + i * 8][tx] = x[base + t];
    yt[ty + i * 8][tx] = (t == 0) ? 0.f : y[base + t - 1];
  }
  __syncthreads();
#pragma unroll
  for (int i = 0; i < 4; ++i) {
    int t = tt * 32 + ty + i * 8;
    int c = ct * 32 + tx;
    unsigned int pk = ((unsigned int)f2bf(yt[tx][ty + i * 8]) << 16) |
                      (unsigned int)f2bf(xt[tx][ty + i * 8]);
    xs32[((size_t)t * 64 + b) * 800 + c] = pk;
  }
}

// ---------------- K4: gx GEMM (m97 structure) ----------------
// gx[r][colp] = xs[r][:] . Wxt[col][:] + bsum[col], stored f16, cols permuted:
// col = q*1024 + g*8 + hc  ->  colp = g*32 + q*8 + hc   (g = WG id in K5)
__global__ __launch_bounds__(256, 2) void gemm_gx(
    const unsigned short* __restrict__ xs, const unsigned short* __restrict__ Wxt,
    const float* __restrict__ bsum, _Float16* __restrict__ gx) {
  __shared__ __align__(16) unsigned short Al[128 * 64];
  __shared__ __align__(16) unsigned short Bl[128 * 64];
  const int tid = threadIdx.x;
  const int w = tid >> 6, l = tid & 63;
  const int l15 = l & 15, l4 = l >> 4;
  const int wm = w >> 1, wn = w & 1;
  // XCD-aware swizzle (8192 % 8 == 0 -> simple form is bijective)
  const int u = (blockIdx.x & 7) * 1024 + (blockIdx.x >> 3);
  const int bm = u >> 5, bn = u & 31;

  f32x4 acc[4][4];
#pragma unroll
  for (int i = 0; i < 4; ++i)
#pragma unroll
    for (int j = 0; j < 4; ++j) acc[i][j] = (f32x4){0.f, 0.f, 0.f, 0.f};

  const int srow = w * 8 + (l >> 3);   // + rnd*32
  const int scol = (l & 7) * 8;

  for (int kt = 0; kt < 25; ++kt) {
#pragma unroll
    for (int rnd = 0; rnd < 4; ++rnd) {
      int row = rnd * 32 + srow;
      gload_lds16(xs + ((size_t)(bm * 128 + row)) * 1600 + kt * 64 + scol,
                  Al + rnd * 2048 + w * 512);
      gload_lds16(Wxt + ((size_t)(bn * 128 + row)) * 1600 + kt * 64 + scol,
                  Bl + rnd * 2048 + w * 512);
    }
    __syncthreads();
#pragma unroll
    for (int kk = 0; kk < 64; kk += 32) {
      short8 av[4], bv[4];
#pragma unroll
      for (int mf = 0; mf < 4; ++mf)
        av[mf] = *(const short8*)&Al[(wm * 64 + mf * 16 + l15) * 64 + kk + l4 * 8];
#pragma unroll
      for (int nf = 0; nf < 4; ++nf)
        bv[nf] = *(const short8*)&Bl[(wn * 64 + nf * 16 + l15) * 64 + kk + l4 * 8];
#pragma unroll
      for (int mf = 0; mf < 4; ++mf)
#pragma unroll
        for (int nf = 0; nf < 4; ++nf)
          acc[mf][nf] = __builtin_amdgcn_mfma_f32_16x16x32_bf16(
              av[mf], bv[nf], acc[mf][nf], 0, 0, 0);
    }
    __syncthreads();
  }
  // epilogue: + bias, permute cols, store f16
#pragma unroll
  for (int nf = 0; nf < 4; ++nf) {
    int col = bn * 128 + wn * 64 + nf * 16 + l15;
    float bs = bsum[col];
    int colp = ((col & 1023) >> 3) * 32 + (col >> 10) * 8 + (col & 7);
#pragma unroll
    for (int mf = 0; mf < 4; ++mf) {
      int row0 = bm * 128 + wm * 64 + mf * 16 + l4 * 4;
#pragma unroll
      for (int j = 0; j < 4; ++j)
        gx[(size_t)(row0 + j) * 4096 + colp] = (_Float16)(acc[mf][nf][j] + bs);
    }
  }
}

// ---------------- grid barrier (sense via generation counter) ----------------
DI void gridbar(unsigned int* cnt, unsigned int* gen, unsigned int n) {
  __syncthreads();
  if (threadIdx.x == 0) {
    __threadfence();  // release: L2 writeback so h stores are device-visible
    unsigned int g = __hip_atomic_load(gen, __ATOMIC_RELAXED, __HIP_MEMORY_SCOPE_AGENT);
    unsigned int a = __hip_atomic_fetch_add(cnt, 1u, __ATOMIC_RELAXED, __HIP_MEMORY_SCOPE_AGENT);
    if (a == n - 1u) {
      __hip_atomic_store(cnt, 0u, __ATOMIC_RELAXED, __HIP_MEMORY_SCOPE_AGENT);
      __hip_atomic_store(gen, g + 1u, __ATOMIC_RELEASE, __HIP_MEMORY_SCOPE_AGENT);
    } else {
      while (__hip_atomic_load(gen, __ATOMIC_RELAXED, __HIP_MEMORY_SCOPE_AGENT) == g)
        __builtin_amdgcn_s_sleep(2);
    }
    __threadfence();  // acquire: invalidate L1/L2 before next h staging
  }
  __syncthreads();
}

// ---------------- K5: persistent LSTM recurrence ----------------
// 128 WGs x 512 thr (8 waves, 2/SIMD). WG g owns h-cols [g*8, g*8+8).
// Wh slice lives in VGPRs (32 B-frags = 128 VGPR). h broadcast via swizzled
// bf16 triple buffer in ws; ONE grid barrier per step (safe with 3 buffers).
__global__ __launch_bounds__(512, 2) void lstm_seq(
    const _Float16* __restrict__ gx, const unsigned short* __restrict__ Wht,
    const float* __restrict__ subj, const float* __restrict__ Winit,
    const float* __restrict__ binit, float* __restrict__ out,
    unsigned short* __restrict__ hbuf, unsigned int* __restrict__ bar) {
  const int g = blockIdx.x;
  const int tid = threadIdx.x;
  const int w = tid >> 6, l = tid & 63;
  const int m = w & 3, nh = w >> 2;
  const int l15 = l & 15, l4 = l >> 4;
  const int lc = nh * 16 + l15;     // local gate-col 0..31, lc = hc*4 + q
  const int q = lc & 3, hc = lc >> 2;
  const int ghc = g * 8 + hc;       // global h-col
  const int ncol = q * 1024 + ghc;  // global gate-col
  const int rbase = m * 16 + l4 * 4;

  __shared__ __align__(16) unsigned short hls[65536];  // 128 KB

  // Wh B-fragments, resident for all 512 steps
  short8 Bf[32];
  {
    const unsigned short* wp = Wht + (size_t)ncol * 1024 + l4 * 8;
#pragma unroll
    for (int kk = 0; kk < 32; ++kk) Bf[kk] = *(const short8*)(wp + kk * 32);
  }

  // c0 = subject_id @ W_init + b_init (fp32, replicated over the 4 q-lanes)
  float c[4];
#pragma unroll
  for (int j = 0; j < 4; ++j) {
    int r = rbase + j;
    float a = binit[ghc];
    for (int k = 0; k < 87; ++k) a += subj[r * 87 + k] * Winit[k * 1024 + ghc];
    c[j] = a;
  }

  float hq[4][4];  // h_seq reg buffer: [j][slot], lane keeps quarter q of 16-window
  int buf = 0;
  unsigned int* cnt = bar;
  unsigned int* gen = bar + 16;

  for (int t4 = 0; t4 < 128; ++t4) {
#pragma unroll
    for (int js = 0; js < 4; ++js) {
      const int t = t4 * 4 + js;
      const int nxt = (buf == 2) ? 0 : buf + 1;
      // stage h (linear copy; layout already swizzled by producer)
      {
        const unsigned short* hsrc = hbuf + buf * 65536;
#pragma unroll
        for (int i = 0; i < 16; ++i) {
          int off = i * 4096 + w * 512;
          gload_lds16(hsrc + off + l * 8, hls + off);
        }
      }
      // gx prefetch (drained by the same vmcnt(0) at the barrier)
      const _Float16* gp = gx + ((size_t)t * 64 + rbase) * 4096 + g * 32 + q * 8 + hc;
      float gv0 = (float)gp[0];
      float gv1 = (float)gp[4096];
      float gv2 = (float)gp[8192];
      float gv3 = (float)gp[12288];
      __syncthreads();
      // h @ Wh_slice : 32 MFMAs, 2 independent chains
      f32x4 acc0 = {0.f, 0.f, 0.f, 0.f}, acc1 = {0.f, 0.f, 0.f, 0.f};
#pragma unroll
      for (int kk = 0; kk < 32; kk += 2) {
        short8 a0 = *(const short8*)((const char*)hls + hswz(m * 16 + l15, kk * 32 + l4 * 8));
        acc0 = __builtin_amdgcn_mfma_f32_16x16x32_bf16(a0, Bf[kk], acc0, 0, 0, 0);
        short8 a1 = *(const short8*)((const char*)hls + hswz(m * 16 + l15, (kk + 1) * 32 + l4 * 8));
        acc1 = __builtin_amdgcn_mfma_f32_16x16x32_bf16(a1, Bf[kk + 1], acc1, 0, 0, 0);
      }
      f32x4 accs = acc0 + acc1;
      float gvv[4] = {gv0, gv1, gv2, gv3};
#pragma unroll
      for (int j = 0; j < 4; ++j) {
        float gval = accs[j] + gvv[j];
        int base = l & ~3;  // gather f,i,u,o from the 4-lane group
        float fv = sigm(__shfl(gval, base));
        float iv = sigm(__shfl(gval, base + 1));
        float uv = tanh_(__shfl(gval, base + 2));
        float ov = sigm(__shfl(gval, base + 3));
        c[j] = c[j] * fv + iv * uv;
        float hv = ov * tanh_(c[j]);
        if ((t4 & 3) == q) hq[j][js] = hv;   // keep my t-quarter
        if (q == 0) {                        // one writer per (r, h-col)
          int r = rbase + j;
          *(unsigned short*)((char*)hbuf + nxt * 131072 + hswz(r, ghc)) = f2bf(hv);
        }
      }
      buf = nxt;
      gridbar(cnt, gen, gridDim.x);
    }
    if ((t4 & 3) == 3) {  // flush 16-step window: full 64B lines across 4 q-lanes
      int tb = (t4 >> 2) * 16 + q * 4;
#pragma unroll
      for (int j = 0; j < 4; ++j) {
        f32x4 v = {hq[j][0], hq[j][1], hq[j][2], hq[j][3]};
        *(f32x4*)(out + (size_t)(rbase + j) * 524288 + (size_t)ghc * 512 + tb) = v;
      }
    }
  }
  if (q == 0) {  // c_fin
#pragma unroll
    for (int j = 0; j < 4; ++j)
      out[33554432 + (size_t)(rbase + j) * 1024 + ghc] = c[j];
  }
}

// ---------------- launch ----------------
extern "C" void kernel_launch(void* const* d_in, const int* in_sizes, int n_in,
                              void* d_out, int out_size, void* d_ws, size_t ws_size,
                              hipStream_t stream) {
  (void)in_sizes; (void)n_in; (void)out_size;
  if (ws_size < WS_NEED) return;

  const float* x     = (const float*)d_in[0];
  const float* y     = (const float*)d_in[1];
  const float* subj  = (const float*)d_in[2];
  const float* W_fx  = (const float*)d_in[3];
  const float* b_fx  = (const float*)d_in[4];
  const float* W_fh  = (const float*)d_in[5];
  const float* b_fh  = (const float*)d_in[6];
  const float* W_ix  = (const float*)d_in[7];
  const float* b_ix  = (const float*)d_in[8];
  const float* W_ih  = (const float*)d_in[9];
  const float* b_ih  = (const float*)d_in[10];
  const float* W_ux  = (const float*)d_in[11];
  const float* b_ux  = (const float*)d_in[12];
  const float* W_uh  = (const float*)d_in[13];
  const float* b_uh  = (const float*)d_in[14];
  const float* W_ox  = (const float*)d_in[15];
  const float* b_ox  = (const float*)d_in[16];
  const float* W_oh  = (const float*)d_in[17];
  const float* b_oh  = (const float*)d_in[18];
  const float* Winit = (const float*)d_in[19];
  const float* binit = (const float*)d_in[20];
  float* out = (float*)d_out;

  char* ws = (char*)d_ws;
  unsigned short* Wxt  = (unsigned short*)(ws + OFF_WXT);
  unsigned short* Wht  = (unsigned short*)(ws + OFF_WHT);
  float*          bsum = (float*)(ws + OFF_BSUM);
  unsigned int*   xs32 = (unsigned int*)(ws + OFF_XS);
  _Float16*       gx   = (_Float16*)(ws + OFF_GX);
  unsigned short* hbuf = (unsigned short*)(ws + OFF_HBUF);
  unsigned int*   bar  = (unsigned int*)(ws + OFF_BAR);

  // deterministic per-call init: h0 = 0 and barrier state = 0
  hipMemsetAsync(ws + OFF_HBUF, 0, (OFF_BAR - OFF_HBUF) + 256, stream);

  pack_w<<<dim3(50, 128), 256, 0, stream>>>(W_fx, W_ix, W_ux, W_ox, Wxt, 1600);
  pack_w<<<dim3(32, 128), 256, 0, stream>>>(W_fh, W_ih, W_uh, W_oh, Wht, 1024);
  pack_bias<<<16, 256, 0, stream>>>(b_fx, b_ix, b_ux, b_ox, b_fh, b_ih, b_uh, b_oh, bsum);
  xs_pack<<<dim3(16, 25, 64), 256, 0, stream>>>(x, y, xs32);
  gemm_gx<<<8192, 256, 0, stream>>>((const unsigned short*)xs32, Wxt, bsum, gx);

  const _Float16* gxc = gx;
  const unsigned short* whtc = Wht;
  void* ka[8] = {(void*)&gxc, (void*)&whtc, (void*)&subj, (void*)&Winit,
                 (void*)&binit, (void*)&out, (void*)&hbuf, (void*)&bar};
  hipError_t e = hipLaunchCooperativeKernel((const void*)lstm_seq, dim3(128), dim3(512),
                                            ka, 0, stream);
  if (e != hipSuccess) {
    // fallback: plain launch; 128 WGs at 1 WG/CU (128KB LDS) are co-resident on 256 CUs
    lstm_seq<<<128, 512, 0, stream>>>(gxc, whtc, subj, Winit, binit, out, hbuf, bar);
  }
}

// Round 2
// 5867.010 us; speedup vs baseline: 1.6326x; 1.6326x over previous
//
#include <hip/hip_runtime.h>

typedef __attribute__((ext_vector_type(8))) short short8;
typedef __attribute__((ext_vector_type(4))) float f32x4;
typedef unsigned long long u64_t;

#define DI __device__ __forceinline__

// ---------------- helpers ----------------
DI unsigned short f2bf(float f) {            // RNE float->bf16
  unsigned int u = __float_as_uint(f);
  u += 0x7FFFu + ((u >> 16) & 1u);
  return (unsigned short)(u >> 16);
}

DI void gload_lds16(const void* g, void* l) { // async global->LDS, 16B/lane
  __builtin_amdgcn_global_load_lds(
      (const __attribute__((address_space(1))) unsigned int*)g,
      (__attribute__((address_space(3))) unsigned int*)l, 16, 0, 0);
}

DI float sigm(float x) { return 1.f / (1.f + __expf(-x)); }
DI float tanh_(float x) { return 1.f - 2.f / (__expf(2.f * x) + 1.f); }

// ---------------- sizes / workspace layout ----------------
// B=64 C=800 T=512 H=1024 IN=1600 4H=4096 TB=32768
static constexpr size_t OFF_WXT  = 0;                       // bf16 [4096][1600]
static constexpr size_t OFF_WHT  = 13107200;                // bf16 [4096][1024]
static constexpr size_t OFF_BSUM = OFF_WHT + 8388608;       // f32  [4096] (bx+bh)
static constexpr size_t OFF_XS   = OFF_BSUM + 16384;        // u32  [32768][800] (bf16 x,y interleaved)
static constexpr size_t OFF_GX   = OFF_XS + 104857600;      // f16  [32768][4096] (col-permuted)
static constexpr size_t OFF_HBUF = OFF_GX + 268435456;      // u32  8 grp x 2 buf x [8][512]
static constexpr size_t OFF_BAR  = OFF_HBUF + 262144;       // u32  8 x 64 (monotonic counters)
static constexpr size_t WS_NEED  = OFF_BAR + 2048;

// ---------------- K1: pack gate weights, transposed, to bf16 ----------------
__global__ __launch_bounds__(256) void pack_w(
    const float* __restrict__ s0, const float* __restrict__ s1,
    const float* __restrict__ s2, const float* __restrict__ s3,
    unsigned short* __restrict__ dst, int K) {
  __shared__ float tile[32][33];
  const int tx = threadIdx.x & 31, ty = threadIdx.x >> 5;
  const int kt = blockIdx.x, nt = blockIdx.y;
  const int q = (nt * 32) >> 10;
  const float* src = (q == 0) ? s0 : (q == 1) ? s1 : (q == 2) ? s2 : s3;
  const int cbase = (nt * 32) & 1023;
#pragma unroll
  for (int i = 0; i < 4; ++i) {
    int k = kt * 32 + ty + i * 8;
    tile[ty + i * 8][tx] = src[(size_t)k * 1024 + cbase + tx];
  }
  __syncthreads();
#pragma unroll
  for (int i = 0; i < 4; ++i) {
    int n = nt * 32 + ty + i * 8;
    dst[(size_t)n * K + kt * 32 + tx] = f2bf(tile[tx][ty + i * 8]);
  }
}

// ---------------- K2: combined bias bx+bh ----------------
__global__ __launch_bounds__(256) void pack_bias(
    const float* bx0, const float* bx1, const float* bx2, const float* bx3,
    const float* bh0, const float* bh1, const float* bh2, const float* bh3,
    float* __restrict__ bsum) {
  int n = blockIdx.x * 256 + threadIdx.x;
  int q = n >> 10, j = n & 1023;
  const float* bx = (q == 0) ? bx0 : (q == 1) ? bx1 : (q == 2) ? bx2 : bx3;
  const float* bh = (q == 0) ? bh0 : (q == 1) ? bh1 : (q == 2) ? bh2 : bh3;
  bsum[n] = bx[j] + bh[j];
}

// ---------------- K3: build xs bf16 [T*B][1600] ----------------
__global__ __launch_bounds__(256) void xs_pack(
    const float* __restrict__ x, const float* __restrict__ y,
    unsigned int* __restrict__ xs32) {
  __shared__ float xt[32][33], yt[32][33];
  const int tx = threadIdx.x & 31, ty = threadIdx.x >> 5;
  const int tt = blockIdx.x, ct = blockIdx.y, b = blockIdx.z;
#pragma unroll
  for (int i = 0; i < 4; ++i) {
    int c = ct * 32 + ty + i * 8;
    int t = tt * 32 + tx;
    size_t base = ((size_t)b * 800 + c) * 512;
    xt[ty + i * 8][tx] = x[base + t];
    yt[ty + i * 8][tx] = (t == 0) ? 0.f : y[base + t - 1];
  }
  __syncthreads();
#pragma unroll
  for (int i = 0; i < 4; ++i) {
    int t = tt * 32 + ty + i * 8;
    int c = ct * 32 + tx;
    unsigned int pk = ((unsigned int)f2bf(yt[tx][ty + i * 8]) << 16) |
                      (unsigned int)f2bf(xt[tx][ty + i * 8]);
    xs32[((size_t)t * 64 + b) * 800 + c] = pk;
  }
}

// ---------------- K4: gx GEMM (m97 structure) ----------------
// col = q*1024 + ghc  ->  colp = (ghc>>5)*128 + (ghc&31)*4 + q
__global__ __launch_bounds__(256, 2) void gemm_gx(
    const unsigned short* __restrict__ xs, const unsigned short* __restrict__ Wxt,
    const float* __restrict__ bsum, _Float16* __restrict__ gx) {
  __shared__ __align__(16) unsigned short Al[128 * 64];
  __shared__ __align__(16) unsigned short Bl[128 * 64];
  const int tid = threadIdx.x;
  const int w = tid >> 6, l = tid & 63;
  const int l15 = l & 15, l4 = l >> 4;
  const int wm = w >> 1, wn = w & 1;
  const int u = (blockIdx.x & 7) * 1024 + (blockIdx.x >> 3);
  const int bm = u >> 5, bn = u & 31;

  f32x4 acc[4][4];
#pragma unroll
  for (int i = 0; i < 4; ++i)
#pragma unroll
    for (int j = 0; j < 4; ++j) acc[i][j] = (f32x4){0.f, 0.f, 0.f, 0.f};

  const int srow = w * 8 + (l >> 3);
  const int scol = (l & 7) * 8;

  for (int kt = 0; kt < 25; ++kt) {
#pragma unroll
    for (int rnd = 0; rnd < 4; ++rnd) {
      int row = rnd * 32 + srow;
      gload_lds16(xs + ((size_t)(bm * 128 + row)) * 1600 + kt * 64 + scol,
                  Al + rnd * 2048 + w * 512);
      gload_lds16(Wxt + ((size_t)(bn * 128 + row)) * 1600 + kt * 64 + scol,
                  Bl + rnd * 2048 + w * 512);
    }
    __syncthreads();
#pragma unroll
    for (int kk = 0; kk < 64; kk += 32) {
      short8 av[4], bv[4];
#pragma unroll
      for (int mf = 0; mf < 4; ++mf)
        av[mf] = *(const short8*)&Al[(wm * 64 + mf * 16 + l15) * 64 + kk + l4 * 8];
#pragma unroll
      for (int nf = 0; nf < 4; ++nf)
        bv[nf] = *(const short8*)&Bl[(wn * 64 + nf * 16 + l15) * 64 + kk + l4 * 8];
#pragma unroll
      for (int mf = 0; mf < 4; ++mf)
#pragma unroll
        for (int nf = 0; nf < 4; ++nf)
          acc[mf][nf] = __builtin_amdgcn_mfma_f32_16x16x32_bf16(
              av[mf], bv[nf], acc[mf][nf], 0, 0, 0);
    }
    __syncthreads();
  }
#pragma unroll
  for (int nf = 0; nf < 4; ++nf) {
    int col = bn * 128 + wn * 64 + nf * 16 + l15;
    float bs = bsum[col];
    int ghc = col & 1023;
    int colp = (ghc >> 5) * 128 + (ghc & 31) * 4 + (col >> 10);
#pragma unroll
    for (int mf = 0; mf < 4; ++mf) {
      int row0 = bm * 128 + wm * 64 + mf * 16 + l4 * 4;
#pragma unroll
      for (int j = 0; j < 4; ++j)
        gx[(size_t)(row0 + j) * 4096 + colp] = (_Float16)(acc[mf][nf][j] + bs);
    }
  }
}

// ---------------- K5: persistent LSTM recurrence, 8 independent groups -------
// group gg = blockIdx&7 owns batch rows [gg*8, gg*8+8); 32 WGs per group.
// WG cwg owns h-cols [cwg*32, cwg*32+32) (=128 gate-cols); Wh slice in VGPRs.
// h exchanged via agent-scope sc0sc1 loads/stores (no cache fences); per-group
// monotonic barrier counter; double-buffered h (safe: stage precedes arrive).
__global__ __launch_bounds__(512, 2) void lstm_seq(
    const _Float16* __restrict__ gx, const unsigned short* __restrict__ Wht,
    const float* __restrict__ subj, const float* __restrict__ Winit,
    const float* __restrict__ binit, float* __restrict__ out,
    unsigned int* __restrict__ hbuf, unsigned int* __restrict__ bar) {
  const int gg  = blockIdx.x & 7;    // group (XCD-aligned under round-robin)
  const int cwg = blockIdx.x >> 3;   // col-chunk in group, 0..31
  const int tid = threadIdx.x;
  const int w = tid >> 6, l = tid & 63;
  const int l15 = l & 15, l4 = l >> 4;
  const int lc  = w * 16 + l15;          // local gate-col 0..127
  const int q   = lc & 3, hcl = lc >> 2; // gate id, local h-col 0..31
  const int ghc = cwg * 32 + hcl;        // group h-col 0..1023
  const int swzA = (l15 & 7) << 4;

  __shared__ __align__(16) unsigned short hls[16 * 1024];  // 32 KB: [16 rows][1024]

  // zero pad rows 8..15 once (MFMA M=16, rows 8..15 are discarded padding)
  for (int i = tid; i < 4096; i += 512) ((unsigned int*)hls)[4096 + i] = 0;

  // Wh B-fragments (128 VGPR), resident across all 512 steps
  short8 Bf[32];
  {
    const unsigned short* wp = Wht + (size_t)(q * 1024 + ghc) * 1024 + l4 * 8;
#pragma unroll
    for (int kk = 0; kk < 32; ++kk) Bf[kk] = *(const short8*)(wp + kk * 32);
  }

  // c0 = subject_id @ W_init + b_init (lane rows l4*4+j; pad lanes clamp)
  float c[4];
#pragma unroll
  for (int j = 0; j < 4; ++j) {
    int b = gg * 8 + ((l4 * 4 + j) & 7);
    float a = binit[ghc];
    for (int k = 0; k < 87; ++k) a += subj[b * 87 + k] * Winit[k * 1024 + ghc];
    c[j] = a;
  }

  unsigned int* cnt = bar + gg * 64;
  const u64_t* hb64 = (const u64_t*)hbuf;
  float hq[4][4];

  for (int t4 = 0; t4 < 128; ++t4) {
#pragma unroll
    for (int js = 0; js < 4; ++js) {
      const int t = t4 * 4 + js;
      const int cur = t & 1, nxt = cur ^ 1;
      // gx prefetch (independent of h; overlaps stage latency)
      const _Float16* gp = gx + ((size_t)(t * 64 + gg * 8)) * 4096 + cwg * 128 + lc;
      float gxv[4];
#pragma unroll
      for (int j = 0; j < 4; ++j)
        gxv[j] = (float)gp[(size_t)((l4 * 4 + j) & 7) * 4096];
      // stage h rows 0..7 into LDS (coherent loads from LLC, swizzled ds_write)
      {
        const u64_t* src = hb64 + (gg * 2 + cur) * 2048;
#pragma unroll
        for (int i = 0; i < 4; ++i) {
          int idx = i * 512 + tid;
          int row = idx >> 8, pp = idx & 255;
          u64_t v = __hip_atomic_load((u64_t*)(src + row * 256 + pp),
                                      __ATOMIC_RELAXED, __HIP_MEMORY_SCOPE_AGENT);
          *(u64_t*)((char*)hls + ((row * 2048 + pp * 8) ^ ((row & 7) << 4))) = v;
        }
      }
      __syncthreads();
      // h @ Wh_slice : 32 MFMAs, 2 chains
      f32x4 acc0 = {0.f, 0.f, 0.f, 0.f}, acc1 = {0.f, 0.f, 0.f, 0.f};
#pragma unroll
      for (int kk = 0; kk < 32; kk += 2) {
        short8 a0 = *(const short8*)((char*)hls + ((l15 * 2048 + kk * 64 + l4 * 16) ^ swzA));
        acc0 = __builtin_amdgcn_mfma_f32_16x16x32_bf16(a0, Bf[kk], acc0, 0, 0, 0);
        short8 a1 = *(const short8*)((char*)hls + ((l15 * 2048 + (kk + 1) * 64 + l4 * 16) ^ swzA));
        acc1 = __builtin_amdgcn_mfma_f32_16x16x32_bf16(a1, Bf[kk + 1], acc1, 0, 0, 0);
      }
      f32x4 accs = acc0 + acc1;
      // gates: f,i,u,o live in the 4 q-lanes of each 4-lane group
#pragma unroll
      for (int j = 0; j < 4; ++j) {
        float gval = accs[j] + gxv[j];
        int base = l & ~3;
        float fv = sigm(__shfl(gval, base));
        float iv = sigm(__shfl(gval, base + 1));
        float uv = tanh_(__shfl(gval, base + 2));
        float ov = sigm(__shfl(gval, base + 3));
        c[j] = c[j] * fv + iv * uv;
        float hv = ov * tanh_(c[j]);
        if ((t4 & 3) == q) hq[j][js] = hv;   // keep my t-quarter of 16-window
        float hv_hi = __shfl(hv, l | 4);     // all lanes execute (no divergence)
        if ((l15 & 7) == 0 && l4 < 2) {      // writers: 2 pairs/wave/row
          unsigned int pk = (unsigned int)f2bf(hv) |
                            ((unsigned int)f2bf(hv_hi) << 16);
          int row = l4 * 4 + j;
          int pairi = cwg * 16 + (hcl >> 1);
          __hip_atomic_store(hbuf + (gg * 2 + nxt) * 4096 + row * 512 + pairi, pk,
                             __ATOMIC_RELAXED, __HIP_MEMORY_SCOPE_AGENT);
        }
      }
      // group barrier: drain stores -> arrive -> poll (monotonic, no fences)
      asm volatile("s_waitcnt vmcnt(0)" ::: "memory");
      __syncthreads();
      if (tid == 0)
        __hip_atomic_fetch_add(cnt, 1u, __ATOMIC_RELAXED, __HIP_MEMORY_SCOPE_AGENT);
      if (l == 0) {
        unsigned int tgt = 32u * (unsigned int)(t + 1);
        while (__hip_atomic_load(cnt, __ATOMIC_RELAXED, __HIP_MEMORY_SCOPE_AGENT) < tgt)
          __builtin_amdgcn_s_sleep(1);
      }
    }
    if ((t4 & 3) == 3) {  // flush 16-step window: 64B lines across 4 q-lanes
      int tb = (t4 >> 2) * 16 + q * 4;
      if (l4 < 2) {
#pragma unroll
        for (int j = 0; j < 4; ++j) {
          f32x4 v = {hq[j][0], hq[j][1], hq[j][2], hq[j][3]};
          *(f32x4*)(out + (size_t)(gg * 8 + l4 * 4 + j) * 524288 +
                    (size_t)ghc * 512 + tb) = v;
        }
      }
    }
  }
  if (q == 0 && l4 < 2) {  // c_fin
#pragma unroll
    for (int j = 0; j < 4; ++j)
      out[33554432 + (size_t)(gg * 8 + l4 * 4 + j) * 1024 + ghc] = c[j];
  }
}

// ---------------- launch ----------------
extern "C" void kernel_launch(void* const* d_in, const int* in_sizes, int n_in,
                              void* d_out, int out_size, void* d_ws, size_t ws_size,
                              hipStream_t stream) {
  (void)in_sizes; (void)n_in; (void)out_size;
  if (ws_size < WS_NEED) return;

  const float* x     = (const float*)d_in[0];
  const float* y     = (const float*)d_in[1];
  const float* subj  = (const float*)d_in[2];
  const float* W_fx  = (const float*)d_in[3];
  const float* b_fx  = (const float*)d_in[4];
  const float* W_fh  = (const float*)d_in[5];
  const float* b_fh  = (const float*)d_in[6];
  const float* W_ix  = (const float*)d_in[7];
  const float* b_ix  = (const float*)d_in[8];
  const float* W_ih  = (const float*)d_in[9];
  const float* b_ih  = (const float*)d_in[10];
  const float* W_ux  = (const float*)d_in[11];
  const float* b_ux  = (const float*)d_in[12];
  const float* W_uh  = (const float*)d_in[13];
  const float* b_uh  = (const float*)d_in[14];
  const float* W_ox  = (const float*)d_in[15];
  const float* b_ox  = (const float*)d_in[16];
  const float* W_oh  = (const float*)d_in[17];
  const float* b_oh  = (const float*)d_in[18];
  const float* Winit = (const float*)d_in[19];
  const float* binit = (const float*)d_in[20];
  float* out = (float*)d_out;

  char* ws = (char*)d_ws;
  unsigned short* Wxt  = (unsigned short*)(ws + OFF_WXT);
  unsigned short* Wht  = (unsigned short*)(ws + OFF_WHT);
  float*          bsum = (float*)(ws + OFF_BSUM);
  unsigned int*   xs32 = (unsigned int*)(ws + OFF_XS);
  _Float16*       gx   = (_Float16*)(ws + OFF_GX);
  unsigned int*   hbuf = (unsigned int*)(ws + OFF_HBUF);
  unsigned int*   bar  = (unsigned int*)(ws + OFF_BAR);

  // deterministic per-call init: h0 = 0 and barrier counters = 0
  hipMemsetAsync(ws + OFF_HBUF, 0, WS_NEED - OFF_HBUF, stream);

  pack_w<<<dim3(50, 128), 256, 0, stream>>>(W_fx, W_ix, W_ux, W_ox, Wxt, 1600);
  pack_w<<<dim3(32, 128), 256, 0, stream>>>(W_fh, W_ih, W_uh, W_oh, Wht, 1024);
  pack_bias<<<16, 256, 0, stream>>>(b_fx, b_ix, b_ux, b_ox, b_fh, b_ih, b_uh, b_oh, bsum);
  xs_pack<<<dim3(16, 25, 64), 256, 0, stream>>>(x, y, xs32);
  gemm_gx<<<8192, 256, 0, stream>>>((const unsigned short*)xs32, Wxt, bsum, gx);

  const _Float16* gxc = gx;
  const unsigned short* whtc = Wht;
  void* ka[8] = {(void*)&gxc, (void*)&whtc, (void*)&subj, (void*)&Winit,
                 (void*)&binit, (void*)&out, (void*)&hbuf, (void*)&bar};
  hipError_t e = hipLaunchCooperativeKernel((const void*)lstm_seq, dim3(256), dim3(512),
                                            ka, 0, stream);
  if (e != hipSuccess) {
    // fallback: plain launch; 256 WGs at 1 WG/CU (launch_bounds caps VGPR<=256,
    // LDS 32KB) are co-resident on 256 CUs
    lstm_seq<<<256, 512, 0, stream>>>(gxc, whtc, subj, Winit, binit, out, hbuf, bar);
  }
}

// Round 3
// 3217.247 us; speedup vs baseline: 2.9772x; 1.8236x over previous
//
#include <hip/hip_runtime.h>

typedef __attribute__((ext_vector_type(8))) short short8;
typedef __attribute__((ext_vector_type(4))) float f32x4;
typedef __attribute__((ext_vector_type(4))) _Float16 f16x4;
typedef unsigned long long u64_t;

#define DI __device__ __forceinline__

// ---------------- helpers ----------------
DI unsigned short f2bf(float f) {            // RNE float->bf16
  unsigned int u = __float_as_uint(f);
  u += 0x7FFFu + ((u >> 16) & 1u);
  return (unsigned short)(u >> 16);
}

DI void gload_lds16(const void* g, void* l) { // async global->LDS, 16B/lane
  __builtin_amdgcn_global_load_lds(
      (const __attribute__((address_space(1))) unsigned int*)g,
      (__attribute__((address_space(3))) unsigned int*)l, 16, 0, 0);
}

DI float sigm(float x) { return 1.f / (1.f + __expf(-x)); }
DI float tanh_(float x) { return 1.f - 2.f / (__expf(2.f * x) + 1.f); }

// ---------------- sizes / workspace layout ----------------
// B=64 C=800 T=512 H=1024 IN=1600 4H=4096 TB=32768
static constexpr size_t OFF_WXT  = 0;                       // bf16 [4096][1600]
static constexpr size_t OFF_WHT  = 13107200;                // bf16 [4096][1024]
static constexpr size_t OFF_BSUM = OFF_WHT + 8388608;       // f32  [4096] (bx+bh)
static constexpr size_t OFF_XS   = OFF_BSUM + 16384;        // u32  [32768][800] (bf16 x,y interleaved)
static constexpr size_t OFF_GX   = OFF_XS + 104857600;      // f16  [32768][4096] (col-permuted)
static constexpr size_t OFF_HBUF = OFF_GX + 268435456;      // u32  8 grp x 2 buf x [8][512]
static constexpr size_t OFF_BAR  = OFF_HBUF + 262144;       // u32  8 x 32 arrival flags
static constexpr size_t WS_NEED  = OFF_BAR + 2048;

// ---------------- K1: pack gate weights, transposed, to bf16 ----------------
__global__ __launch_bounds__(256) void pack_w(
    const float* __restrict__ s0, const float* __restrict__ s1,
    const float* __restrict__ s2, const float* __restrict__ s3,
    unsigned short* __restrict__ dst, int K) {
  __shared__ float tile[32][33];
  const int tx = threadIdx.x & 31, ty = threadIdx.x >> 5;
  const int kt = blockIdx.x, nt = blockIdx.y;
  const int q = (nt * 32) >> 10;
  const float* src = (q == 0) ? s0 : (q == 1) ? s1 : (q == 2) ? s2 : s3;
  const int cbase = (nt * 32) & 1023;
#pragma unroll
  for (int i = 0; i < 4; ++i) {
    int k = kt * 32 + ty + i * 8;
    tile[ty + i * 8][tx] = src[(size_t)k * 1024 + cbase + tx];
  }
  __syncthreads();
#pragma unroll
  for (int i = 0; i < 4; ++i) {
    int n = nt * 32 + ty + i * 8;
    dst[(size_t)n * K + kt * 32 + tx] = f2bf(tile[tx][ty + i * 8]);
  }
}

// ---------------- K2: combined bias bx+bh ----------------
__global__ __launch_bounds__(256) void pack_bias(
    const float* bx0, const float* bx1, const float* bx2, const float* bx3,
    const float* bh0, const float* bh1, const float* bh2, const float* bh3,
    float* __restrict__ bsum) {
  int n = blockIdx.x * 256 + threadIdx.x;
  int q = n >> 10, j = n & 1023;
  const float* bx = (q == 0) ? bx0 : (q == 1) ? bx1 : (q == 2) ? bx2 : bx3;
  const float* bh = (q == 0) ? bh0 : (q == 1) ? bh1 : (q == 2) ? bh2 : bh3;
  bsum[n] = bx[j] + bh[j];
}

// ---------------- K3: build xs bf16 [T*B][1600] ----------------
__global__ __launch_bounds__(256) void xs_pack(
    const float* __restrict__ x, const float* __restrict__ y,
    unsigned int* __restrict__ xs32) {
  __shared__ float xt[32][33], yt[32][33];
  const int tx = threadIdx.x & 31, ty = threadIdx.x >> 5;
  const int tt = blockIdx.x, ct = blockIdx.y, b = blockIdx.z;
#pragma unroll
  for (int i = 0; i < 4; ++i) {
    int c = ct * 32 + ty + i * 8;
    int t = tt * 32 + tx;
    size_t base = ((size_t)b * 800 + c) * 512;
    xt[ty + i * 8][tx] = x[base + t];
    yt[ty + i * 8][tx] = (t == 0) ? 0.f : y[base + t - 1];
  }
  __syncthreads();
#pragma unroll
  for (int i = 0; i < 4; ++i) {
    int t = tt * 32 + ty + i * 8;
    int c = ct * 32 + tx;
    unsigned int pk = ((unsigned int)f2bf(yt[tx][ty + i * 8]) << 16) |
                      (unsigned int)f2bf(xt[tx][ty + i * 8]);
    xs32[((size_t)t * 64 + b) * 800 + c] = pk;
  }
}

// ---------------- K4: gx GEMM (m97 structure) ----------------
// col = q*1024 + ghc  ->  colp = ghc*4 + q  (4 gates of an h-col adjacent)
__global__ __launch_bounds__(256, 2) void gemm_gx(
    const unsigned short* __restrict__ xs, const unsigned short* __restrict__ Wxt,
    const float* __restrict__ bsum, _Float16* __restrict__ gx) {
  __shared__ __align__(16) unsigned short Al[128 * 64];
  __shared__ __align__(16) unsigned short Bl[128 * 64];
  const int tid = threadIdx.x;
  const int w = tid >> 6, l = tid & 63;
  const int l15 = l & 15, l4 = l >> 4;
  const int wm = w >> 1, wn = w & 1;
  const int u = (blockIdx.x & 7) * 1024 + (blockIdx.x >> 3);
  const int bm = u >> 5, bn = u & 31;

  f32x4 acc[4][4];
#pragma unroll
  for (int i = 0; i < 4; ++i)
#pragma unroll
    for (int j = 0; j < 4; ++j) acc[i][j] = (f32x4){0.f, 0.f, 0.f, 0.f};

  const int srow = w * 8 + (l >> 3);
  const int scol = (l & 7) * 8;

  for (int kt = 0; kt < 25; ++kt) {
#pragma unroll
    for (int rnd = 0; rnd < 4; ++rnd) {
      int row = rnd * 32 + srow;
      gload_lds16(xs + ((size_t)(bm * 128 + row)) * 1600 + kt * 64 + scol,
                  Al + rnd * 2048 + w * 512);
      gload_lds16(Wxt + ((size_t)(bn * 128 + row)) * 1600 + kt * 64 + scol,
                  Bl + rnd * 2048 + w * 512);
    }
    __syncthreads();
#pragma unroll
    for (int kk = 0; kk < 64; kk += 32) {
      short8 av[4], bv[4];
#pragma unroll
      for (int mf = 0; mf < 4; ++mf)
        av[mf] = *(const short8*)&Al[(wm * 64 + mf * 16 + l15) * 64 + kk + l4 * 8];
#pragma unroll
      for (int nf = 0; nf < 4; ++nf)
        bv[nf] = *(const short8*)&Bl[(wn * 64 + nf * 16 + l15) * 64 + kk + l4 * 8];
#pragma unroll
      for (int mf = 0; mf < 4; ++mf)
#pragma unroll
        for (int nf = 0; nf < 4; ++nf)
          acc[mf][nf] = __builtin_amdgcn_mfma_f32_16x16x32_bf16(
              av[mf], bv[nf], acc[mf][nf], 0, 0, 0);
    }
    __syncthreads();
  }
#pragma unroll
  for (int nf = 0; nf < 4; ++nf) {
    int col = bn * 128 + wn * 64 + nf * 16 + l15;
    float bs = bsum[col];
    int colp = (col & 1023) * 4 + (col >> 10);
#pragma unroll
    for (int mf = 0; mf < 4; ++mf) {
      int row0 = bm * 128 + wm * 64 + mf * 16 + l4 * 4;
#pragma unroll
      for (int j = 0; j < 4; ++j)
        gx[(size_t)(row0 + j) * 4096 + colp] = (_Float16)(acc[mf][nf][j] + bs);
    }
  }
}

// ---------------- K5: persistent LSTM recurrence ----------------
// 8 groups (gg=blockIdx&7) x 32 WGs (cwg), 512 thr, 96KB LDS -> 1 WG/CU.
// Wave w: ws=w&1 (h-col half), kq=w>>1 (K-slice of 256). Each wave computes
// ALL 4 gates for its 16 h-cols over its K-slice (A-frag reused 4x), partials
// reduced via LDS; finalizer waves (kq=0) hold all 4 gates per lane -> no
// shuffles. Barrier: per-WG monotonic flag array + single-wave ballot poll.
__global__ __launch_bounds__(512, 2) void lstm_seq(
    const _Float16* __restrict__ gx, const unsigned short* __restrict__ Wht,
    const float* __restrict__ subj, const float* __restrict__ Winit,
    const float* __restrict__ binit, float* __restrict__ out,
    unsigned int* __restrict__ hbuf, unsigned int* __restrict__ bar) {
  const int gg  = blockIdx.x & 7;
  const int cwg = blockIdx.x >> 3;
  const int tid = threadIdx.x;
  const int w = tid >> 6, l = tid & 63;
  const int l15 = l & 15, l4 = l >> 4;
  const int ws = w & 1, kq = w >> 1;
  const int ghc = cwg * 32 + ws * 16 + l15;  // this lane's h-col (as B operand)

  __shared__ __align__(16) char smem[98304];  // 96 KB -> exclusive CU
  char* part = smem + 16384;                  // partial sums [ws][kq-1][g][lane]

  // Wh B-fragments: Bf[g*8+ks] = Wht[g*1024+ghc][kq*256+ks*32+l4*8 ..+8]
  short8 Bf[32];
  {
    const unsigned short* wp =
        Wht + (size_t)(cwg * 32 + ws * 16 + l15) * 1024 + kq * 256 + l4 * 8;
#pragma unroll
    for (int g = 0; g < 4; ++g)
#pragma unroll
      for (int ks = 0; ks < 8; ++ks)
        Bf[g * 8 + ks] = *(const short8*)(wp + (size_t)g * 1048576 + ks * 32);
  }

  // c0 = subject_id @ W_init + b_init (finalizer lanes only)
  float c[4], hq[4][8];
  if (w < 2 && l4 < 2) {
#pragma unroll
    for (int j = 0; j < 4; ++j) {
      int b = gg * 8 + l4 * 4 + j;
      float a = binit[ghc];
      for (int k = 0; k < 87; ++k) a += subj[b * 87 + k] * Winit[k * 1024 + ghc];
      c[j] = a;
    }
  }

  unsigned int* flags = bar + gg * 32;
  const u64_t* hb64 = (const u64_t*)hbuf;

  for (int t8 = 0; t8 < 64; ++t8) {
#pragma unroll
    for (int s = 0; s < 8; ++s) {
      const int t = t8 * 8 + s;
      const int cur = s & 1, nxt = cur ^ 1;
      // 1. poll: wave 7's 32 lanes read the 32 WG flags, ballot
      if (w == 7) {
        const unsigned tgt = (unsigned)t;
        for (;;) {
          unsigned f = 0xFFFFFFFFu;
          if (l < 32)
            f = __hip_atomic_load(flags + l, __ATOMIC_RELAXED, __HIP_MEMORY_SCOPE_AGENT);
          if (__all(f >= tgt)) break;
          __builtin_amdgcn_s_sleep(2);
        }
      }
      __syncthreads();  // A: h(t) visible to all
      // 2. stage h rows 0..7 (16 KB) into LDS, XOR-swizzled
      {
        const u64_t* src = hb64 + (gg * 2 + cur) * 2048;
#pragma unroll
        for (int i = 0; i < 4; ++i) {
          int idx = i * 512 + tid;
          int row = idx >> 8, pp = idx & 255;
          u64_t v = __hip_atomic_load((u64_t*)(src + row * 256 + pp),
                                      __ATOMIC_RELAXED, __HIP_MEMORY_SCOPE_AGENT);
          *(u64_t*)(smem + ((row * 2048 + pp * 8) ^ ((row & 7) << 4))) = v;
        }
      }
      // 3. gx loads (finalizer lanes; consumed after sync C)
      f16x4 gxq[4];
      if (w < 2 && l4 < 2) {
        const _Float16* gp =
            gx + ((size_t)(t * 64 + gg * 8 + l4 * 4)) * 4096 + ghc * 4;
#pragma unroll
        for (int j = 0; j < 4; ++j) gxq[j] = *(const f16x4*)(gp + (size_t)j * 4096);
      }
      __syncthreads();  // B: staged h readable
      // 4. MFMA: 8 A-reads, each feeds 4 gate-MFMAs
      f32x4 acc[4];
#pragma unroll
      for (int g = 0; g < 4; ++g) acc[g] = (f32x4){0.f, 0.f, 0.f, 0.f};
#pragma unroll
      for (int ks = 0; ks < 8; ++ks) {
        short8 a = *(const short8*)(
            smem + (((l15 & 7) * 2048 + kq * 512 + ks * 64 + l4 * 16) ^ ((l15 & 7) << 4)));
#pragma unroll
        for (int g = 0; g < 4; ++g)
          acc[g] = __builtin_amdgcn_mfma_f32_16x16x32_bf16(a, Bf[g * 8 + ks], acc[g], 0, 0, 0);
      }
      // 5. K-partials to LDS (waves kq>0)
      if (w >= 2) {
        char* pb = part + (ws * 3 + kq - 1) * 4096;
#pragma unroll
        for (int g = 0; g < 4; ++g) *(f32x4*)(pb + g * 1024 + l * 16) = acc[g];
      }
      __syncthreads();  // C: partials readable
      // 6. reduce + gates + h-store (finalizer waves kq=0)
      if (w < 2) {
        f32x4 red[4];
#pragma unroll
        for (int g = 0; g < 4; ++g) {
          red[g] = acc[g];
#pragma unroll
          for (int kk = 0; kk < 3; ++kk)
            red[g] += *(const f32x4*)(part + (ws * 3 + kk) * 4096 + g * 1024 + l * 16);
        }
        if (l4 < 2) {
#pragma unroll
          for (int j = 0; j < 4; ++j) {
            float fv = sigm(red[0][j] + (float)gxq[j][0]);
            float iv = sigm(red[1][j] + (float)gxq[j][1]);
            float uv = tanh_(red[2][j] + (float)gxq[j][2]);
            float ov = sigm(red[3][j] + (float)gxq[j][3]);
            c[j] = c[j] * fv + iv * uv;
            float hv = ov * tanh_(c[j]);
            hq[j][s] = hv;
            float hn = __shfl_xor(hv, 1);  // neighbor h-col for u32 packing
            if (!(l15 & 1)) {
              unsigned int pk = (unsigned int)f2bf(hv) | ((unsigned int)f2bf(hn) << 16);
              __hip_atomic_store(
                  hbuf + (gg * 2 + nxt) * 4096 + (l4 * 4 + j) * 512 +
                      cwg * 16 + ws * 8 + (l15 >> 1),
                  pk, __ATOMIC_RELAXED, __HIP_MEMORY_SCOPE_AGENT);
            }
          }
        }
      }
      asm volatile("s_waitcnt vmcnt(0)" ::: "memory");  // drain h-stores
      __syncthreads();  // D: both finalizer waves drained
      if (tid == 0)
        __hip_atomic_store(bar + gg * 32 + cwg, (unsigned)(t + 1),
                           __ATOMIC_RELAXED, __HIP_MEMORY_SCOPE_AGENT);
    }
    // flush 8-step h_seq window (32B chunks per lane)
    if (w < 2 && l4 < 2) {
      int tb = t8 * 8;
#pragma unroll
      for (int j = 0; j < 4; ++j) {
        f32x4 v0 = {hq[j][0], hq[j][1], hq[j][2], hq[j][3]};
        f32x4 v1 = {hq[j][4], hq[j][5], hq[j][6], hq[j][7]};
        float* op = out + (size_t)(gg * 8 + l4 * 4 + j) * 524288 + (size_t)ghc * 512 + tb;
        *(f32x4*)op = v0;
        *(f32x4*)(op + 4) = v1;
      }
    }
  }
  if (w < 2 && l4 < 2) {  // c_fin
#pragma unroll
    for (int j = 0; j < 4; ++j)
      out[33554432 + (size_t)(gg * 8 + l4 * 4 + j) * 1024 + ghc] = c[j];
  }
}

// ---------------- launch ----------------
extern "C" void kernel_launch(void* const* d_in, const int* in_sizes, int n_in,
                              void* d_out, int out_size, void* d_ws, size_t ws_size,
                              hipStream_t stream) {
  (void)in_sizes; (void)n_in; (void)out_size;
  if (ws_size < WS_NEED) return;

  const float* x     = (const float*)d_in[0];
  const float* y     = (const float*)d_in[1];
  const float* subj  = (const float*)d_in[2];
  const float* W_fx  = (const float*)d_in[3];
  const float* b_fx  = (const float*)d_in[4];
  const float* W_fh  = (const float*)d_in[5];
  const float* b_fh  = (const float*)d_in[6];
  const float* W_ix  = (const float*)d_in[7];
  const float* b_ix  = (const float*)d_in[8];
  const float* W_ih  = (const float*)d_in[9];
  const float* b_ih  = (const float*)d_in[10];
  const float* W_ux  = (const float*)d_in[11];
  const float* b_ux  = (const float*)d_in[12];
  const float* W_uh  = (const float*)d_in[13];
  const float* b_uh  = (const float*)d_in[14];
  const float* W_ox  = (const float*)d_in[15];
  const float* b_ox  = (const float*)d_in[16];
  const float* W_oh  = (const float*)d_in[17];
  const float* b_oh  = (const float*)d_in[18];
  const float* Winit = (const float*)d_in[19];
  const float* binit = (const float*)d_in[20];
  float* out = (float*)d_out;

  char* ws = (char*)d_ws;
  unsigned short* Wxt  = (unsigned short*)(ws + OFF_WXT);
  unsigned short* Wht  = (unsigned short*)(ws + OFF_WHT);
  float*          bsum = (float*)(ws + OFF_BSUM);
  unsigned int*   xs32 = (unsigned int*)(ws + OFF_XS);
  _Float16*       gx   = (_Float16*)(ws + OFF_GX);
  unsigned int*   hbuf = (unsigned int*)(ws + OFF_HBUF);
  unsigned int*   bar  = (unsigned int*)(ws + OFF_BAR);

  // deterministic per-call init: h(0)=0 in both buffers, flags=0
  hipMemsetAsync(ws + OFF_HBUF, 0, WS_NEED - OFF_HBUF, stream);

  pack_w<<<dim3(50, 128), 256, 0, stream>>>(W_fx, W_ix, W_ux, W_ox, Wxt, 1600);
  pack_w<<<dim3(32, 128), 256, 0, stream>>>(W_fh, W_ih, W_uh, W_oh, Wht, 1024);
  pack_bias<<<16, 256, 0, stream>>>(b_fx, b_ix, b_ux, b_ox, b_fh, b_ih, b_uh, b_oh, bsum);
  xs_pack<<<dim3(16, 25, 64), 256, 0, stream>>>(x, y, xs32);
  gemm_gx<<<8192, 256, 0, stream>>>((const unsigned short*)xs32, Wxt, bsum, gx);

  const _Float16* gxc = gx;
  const unsigned short* whtc = Wht;
  void* ka[8] = {(void*)&gxc, (void*)&whtc, (void*)&subj, (void*)&Winit,
                 (void*)&binit, (void*)&out, (void*)&hbuf, (void*)&bar};
  hipError_t e = hipLaunchCooperativeKernel((const void*)lstm_seq, dim3(256), dim3(512),
                                            ka, 0, stream);
  if (e != hipSuccess) {
    // fallback: plain launch; 256 WGs at 1 WG/CU (96KB LDS) co-resident on 256 CUs
    lstm_seq<<<256, 512, 0, stream>>>(gxc, whtc, subj, Winit, binit, out, hbuf, bar);
  }
}